// Round 1
// baseline (182.768 us; speedup 1.0000x reference)
//
#include <hip/hip_runtime.h>
#include <hip/hip_bf16.h>

// Problem constants (fixed by setup_inputs)
#define B_   8
#define D_   4
#define H_   640
#define W_   640
#define HW_  (H_ * W_)       // 409600
#define L_   8
#define BLOCK 256
#define ITER  8              // pixels per thread per pass kernel

// delta_v = 0.5, delta_d = 1.5

__device__ __forceinline__ void fatom_add(float* p, float v) {
    // HW float atomic add (global_atomic_add_f32 / ds_add_f32)
    unsafeAtomicAdd(p, v);
}

// ---------------------------------------------------------------------------
// K0: init workspace (ws is poisoned 0xAA before every timed launch)
// ws layout (elements):
//   int   firstIdx [B*L]   = 64
//   int   secondIdx[B*L]   = 64
//   float cntk     [B*L]   = 64
//   float cntf     [B*L]   = 64
//   float sumemb   [B*L*D] = 256
//   float sumval   [B*L]   = 64
// ---------------------------------------------------------------------------
__global__ void k_init(int* firstIdx, int* secondIdx, float* fbuf) {
    int t = threadIdx.x;
    if (t < B_ * L_) { firstIdx[t] = HW_; secondIdx[t] = HW_; }
    for (int i = t; i < 448; i += blockDim.x) fbuf[i] = 0.0f;
}

// ---------------------------------------------------------------------------
// K1: per-label counts, kernel-region embedding sums, first-occurrence index
// grid: (HW/(BLOCK*ITER), B)
// ---------------------------------------------------------------------------
__global__ __launch_bounds__(BLOCK) void k_pass1(
        const float* __restrict__ emb, const int* __restrict__ inst,
        const float* __restrict__ kern, const float* __restrict__ tmask,
        int* __restrict__ firstIdx, float* __restrict__ cntk,
        float* __restrict__ cntf, float* __restrict__ sumemb) {
    __shared__ int   sFirst[L_];
    __shared__ float sCntK[L_], sCntF[L_];
    __shared__ float sSum[L_ * D_];

    const int tid = threadIdx.x;
    if (tid < L_) { sFirst[tid] = HW_; sCntK[tid] = 0.0f; sCntF[tid] = 0.0f; }
    if (tid < L_ * D_) sSum[tid] = 0.0f;
    __syncthreads();

    const int b    = blockIdx.y;
    const int base = b * HW_;

    #pragma unroll
    for (int it = 0; it < ITER; ++it) {
        int p = blockIdx.x * (BLOCK * ITER) + it * BLOCK + tid;
        int lab  = inst[base + p];
        float tm = tmask[base + p];
        int lf = (tm > 0.5f) ? lab : 0;
        if (lf > 0) {
            atomicMin(&sFirst[lf], p);
            fatom_add(&sCntF[lf], 1.0f);
            float kn = kern[base + p];
            if (kn > 0.5f) {
                fatom_add(&sCntK[lf], 1.0f);
                #pragma unroll
                for (int d = 0; d < D_; ++d)
                    fatom_add(&sSum[lf * D_ + d], emb[(b * D_ + d) * HW_ + p]);
            }
        }
    }
    __syncthreads();

    if (tid >= 1 && tid < L_) {
        atomicMin(&firstIdx[b * L_ + tid], sFirst[tid]);
        fatom_add(&cntf[b * L_ + tid], sCntF[tid]);
        fatom_add(&cntk[b * L_ + tid], sCntK[tid]);
    }
    if (tid >= D_ && tid < L_ * D_)   // skip label 0 sums (mean[0] is zeroed)
        fatom_add(&sumemb[b * L_ * D_ + tid], sSum[tid]);
}

// ---------------------------------------------------------------------------
// K2: second-occurrence index (needs firstIdx)
// ---------------------------------------------------------------------------
__global__ __launch_bounds__(BLOCK) void k_pass2(
        const int* __restrict__ inst, const float* __restrict__ tmask,
        const int* __restrict__ firstIdx, int* __restrict__ secondIdx) {
    __shared__ int sFirst[L_];
    __shared__ int sSecond[L_];

    const int tid = threadIdx.x;
    const int b   = blockIdx.y;
    if (tid < L_) { sFirst[tid] = firstIdx[b * L_ + tid]; sSecond[tid] = HW_; }
    __syncthreads();

    const int base = b * HW_;
    #pragma unroll
    for (int it = 0; it < ITER; ++it) {
        int p = blockIdx.x * (BLOCK * ITER) + it * BLOCK + tid;
        int lab  = inst[base + p];
        float tm = tmask[base + p];
        int lf = (tm > 0.5f) ? lab : 0;
        if (lf > 0 && p != sFirst[lf]) atomicMin(&sSecond[lf], p);
    }
    __syncthreads();

    if (tid >= 1 && tid < L_)
        atomicMin(&secondIdx[b * L_ + tid], sSecond[tid]);
}

// ---------------------------------------------------------------------------
// K3: l_agg inner pass — per-pixel log(relu(cd*dist - dv)^2 + 1), summed/label
// ---------------------------------------------------------------------------
__global__ __launch_bounds__(BLOCK) void k_pass3(
        const float* __restrict__ emb, const int* __restrict__ inst,
        const float* __restrict__ tmask,
        const int* __restrict__ firstIdx, const int* __restrict__ secondIdx,
        const float* __restrict__ cntk, const float* __restrict__ sumemb,
        float* __restrict__ sumval) {
    __shared__ float sMean[L_ * D_];
    __shared__ float sCd[L_];
    __shared__ float sVal[L_];

    const int tid = threadIdx.x;
    const int b   = blockIdx.y;

    if (tid < L_ * D_) {
        int l = tid / D_;
        float c = fmaxf(cntk[b * L_ + l], 1.0f);
        sMean[tid] = (l > 0) ? sumemb[b * L_ * D_ + tid] / c : 0.0f;
    }
    if (tid < L_) {
        float cd = 0.0f;
        if (tid > 0) {
            const float diag = sqrtf((float)(H_ * H_ + W_ * W_));
            int f = min(firstIdx[b * L_ + tid],  HW_ - 1);
            int s = min(secondIdx[b * L_ + tid], HW_ - 1);
            float r0 = (float)(f / W_), c0 = (float)(f % W_);
            float r1 = (float)(s / W_), c1 = (float)(s % W_);
            cd = expf(sqrtf((r0 - c0) * (r0 - c0) + (r1 - c1) * (r1 - c1))
                      / diag * 0.5f);
        }
        sCd[tid]  = cd;
        sVal[tid] = 0.0f;
    }
    __syncthreads();

    const int base = b * HW_;
    #pragma unroll
    for (int it = 0; it < ITER; ++it) {
        int p = blockIdx.x * (BLOCK * ITER) + it * BLOCK + tid;
        int lab  = inst[base + p];
        float tm = tmask[base + p];
        int lf = (tm > 0.5f) ? lab : 0;
        if (lf > 0) {
            float d2 = 0.0f;
            #pragma unroll
            for (int d = 0; d < D_; ++d) {
                float e = emb[(b * D_ + d) * HW_ + p] - sMean[lf * D_ + d];
                d2 += e * e;
            }
            float dist = (d2 > 0.0f) ? sqrtf(d2) : 0.0f;
            float x = sCd[lf] * dist - 0.5f;          // delta_v = 0.5
            if (x > 0.0f) fatom_add(&sVal[lf], logf(x * x + 1.0f));
        }
    }
    __syncthreads();

    if (tid >= 1 && tid < L_)
        fatom_add(&sumval[b * L_ + tid], sVal[tid]);
}

// ---------------------------------------------------------------------------
// K4: epilogue — l_dis, l_reg, l_agg per image; batch mean → out[0]
// ---------------------------------------------------------------------------
__global__ void k_final(const int* __restrict__ firstIdx,
                        const int* __restrict__ secondIdx,
                        const float* __restrict__ cntk,
                        const float* __restrict__ cntf,
                        const float* __restrict__ sumemb,
                        const float* __restrict__ sumval,
                        float* __restrict__ out) {
    __shared__ float sLoss[B_];
    const int b = threadIdx.x;
    if (b < B_) {
        const float diag = sqrtf((float)(H_ * H_ + W_ * W_));
        float mean[L_][D_];
        float ss[L_], tt[L_];
        #pragma unroll
        for (int l = 0; l < L_; ++l) {
            float c = fmaxf(cntk[b * L_ + l], 1.0f);
            #pragma unroll
            for (int d = 0; d < D_; ++d)
                mean[l][d] = (l > 0) ? sumemb[(b * L_ + l) * D_ + d] / c : 0.0f;
            int f = min(firstIdx[b * L_ + l],  HW_ - 1);
            int s = min(secondIdx[b * L_ + l], HW_ - 1);
            float r0 = (float)(f / W_), c0 = (float)(f % W_);
            float r1 = (float)(s / W_), c1 = (float)(s % W_);
            ss[l] = r0 + c0;
            tt[l] = r1 + c1;
        }
        // l_dis: off-diagonal pairs i,j >= 1
        float ldis = 0.0f;
        #pragma unroll
        for (int i = 1; i < L_; ++i) {
            #pragma unroll
            for (int j = 1; j < L_; ++j) {
                if (i == j) continue;
                float d2 = 0.0f;
                #pragma unroll
                for (int d = 0; d < D_; ++d) {
                    float df = mean[i][d] - mean[j][d];
                    d2 += df * df;
                }
                float Dn = (d2 > 0.0f) ? sqrtf(d2) : 0.0f;
                float dx = ss[i] - ss[j], dy = tt[i] - tt[j];
                float dp = sqrtf(dx * dx + dy * dy);
                float coef = 1.0f - 20.0f * expf(-4.0f - 2.5f * dp / diag);
                float x = 3.0f - coef * Dn;            // 2*delta_d = 3.0
                if (x > 0.0f) ldis += logf(x * x + 1.0f);
            }
        }
        ldis *= (1.0f / 42.0f);                        // (L-1)*(L-2)
        // l_reg
        float lreg = 0.0f;
        #pragma unroll
        for (int l = 0; l < L_; ++l) {
            float d2 = 0.0f;
            #pragma unroll
            for (int d = 0; d < D_; ++d) d2 += mean[l][d] * mean[l][d];
            float n = (d2 > 0.0f) ? sqrtf(d2) : 0.0f;
            lreg += logf(n + 1.0f);
        }
        lreg = lreg * (1.0f / L_) * 0.001f;
        // l_agg
        float lagg = 0.0f;
        #pragma unroll
        for (int l = 1; l < L_; ++l)
            lagg += sumval[b * L_ + l] / fmaxf(cntf[b * L_ + l], 1.0f);
        lagg *= (1.0f / (L_ - 1));
        sLoss[b] = lagg + ldis + lreg;
    }
    __syncthreads();
    if (threadIdx.x == 0) {
        float tot = 0.0f;
        #pragma unroll
        for (int i = 0; i < B_; ++i) tot += sLoss[i];
        out[0] = tot * (1.0f / B_);                    // LOSS_WEIGHT = 1
    }
}

extern "C" void kernel_launch(void* const* d_in, const int* in_sizes, int n_in,
                              void* d_out, int out_size, void* d_ws, size_t ws_size,
                              hipStream_t stream) {
    const float* emb   = (const float*)d_in[0];
    const int*   inst  = (const int*)  d_in[1];
    const float* kern  = (const float*)d_in[2];
    const float* tmask = (const float*)d_in[3];
    // d_in[4] = bboxes, unused by the reference

    int*   firstIdx  = (int*)d_ws;
    int*   secondIdx = firstIdx + B_ * L_;
    float* cntk      = (float*)(secondIdx + B_ * L_);
    float* cntf      = cntk + B_ * L_;
    float* sumemb    = cntf + B_ * L_;
    float* sumval    = sumemb + B_ * L_ * D_;
    float* out       = (float*)d_out;

    dim3 grid(HW_ / (BLOCK * ITER), B_);   // (200, 8)

    k_init <<<1, 256, 0, stream>>>(firstIdx, secondIdx, cntk);
    k_pass1<<<grid, BLOCK, 0, stream>>>(emb, inst, kern, tmask,
                                        firstIdx, cntk, cntf, sumemb);
    k_pass2<<<grid, BLOCK, 0, stream>>>(inst, tmask, firstIdx, secondIdx);
    k_pass3<<<grid, BLOCK, 0, stream>>>(emb, inst, tmask, firstIdx, secondIdx,
                                        cntk, sumemb, sumval);
    k_final<<<1, 64, 0, stream>>>(firstIdx, secondIdx, cntk, cntf,
                                  sumemb, sumval, out);
}

// Round 2
// 172.788 us; speedup vs baseline: 1.0578x; 1.0578x over previous
//
#include <hip/hip_runtime.h>
#include <hip/hip_bf16.h>

// Problem constants (fixed by setup_inputs)
#define B_   8
#define D_   4
#define H_   640
#define W_   640
#define HW_  (H_ * W_)       // 409600
#define L_   8
#define NL   (L_ - 1)        // labels 1..7
#define BLOCK 256
#define ITER  8              // pixels per thread per pass kernel

__device__ __forceinline__ void gatom_add(float* p, float v) {
    unsafeAtomicAdd(p, v);   // global_atomic_add_f32
}

// ---------------------------------------------------------------------------
// ws layout (elements):
//   int   firstIdx [B*L]   = 64
//   int   secondIdx[B*L]   = 64
//   float cntk     [B*L]   = 64
//   float cntf     [B*L]   = 64
//   float sumemb   [B*L*D] = 256
//   float sumval   [B*L]   = 64
// ---------------------------------------------------------------------------
__global__ void k_init(int* firstIdx, int* secondIdx, float* fbuf) {
    int t = threadIdx.x;
    if (t < B_ * L_) { firstIdx[t] = HW_; secondIdx[t] = HW_; }
    for (int i = t; i < 448; i += blockDim.x) fbuf[i] = 0.0f;
}

// ---------------------------------------------------------------------------
// K1: per-label counts, kernel-region sums, first+second occurrence — all in
// registers, one shuffle reduction per wave, no per-pixel LDS atomics.
// grid: (HW/(BLOCK*ITER), B)
// ---------------------------------------------------------------------------
__global__ __launch_bounds__(BLOCK) void k_pass1(
        const float* __restrict__ emb, const int* __restrict__ inst,
        const float* __restrict__ kern, const float* __restrict__ tmask,
        int* __restrict__ firstIdx, int* __restrict__ secondIdx,
        float* __restrict__ cntk, float* __restrict__ cntf,
        float* __restrict__ sumemb) {
    __shared__ float sCntF[L_], sCntK[L_], sSum[L_ * D_];
    __shared__ int   sM1[L_], sM2[L_];

    const int tid = threadIdx.x;
    if (tid < L_) { sCntF[tid] = 0.f; sCntK[tid] = 0.f; sM1[tid] = HW_; sM2[tid] = HW_; }
    if (tid < L_ * D_) sSum[tid] = 0.f;
    __syncthreads();

    const int b    = blockIdx.y;
    const int base = b * HW_;

    float cf[NL], ck[NL], sm[NL][D_];
    int   m1[NL], m2[NL];
    #pragma unroll
    for (int l = 0; l < NL; ++l) {
        cf[l] = 0.f; ck[l] = 0.f; m1[l] = HW_; m2[l] = HW_;
        #pragma unroll
        for (int d = 0; d < D_; ++d) sm[l][d] = 0.f;
    }

    #pragma unroll
    for (int it = 0; it < ITER; ++it) {
        int p = blockIdx.x * (BLOCK * ITER) + it * BLOCK + tid;  // increasing in it
        int lab  = inst[base + p];
        float tm = tmask[base + p];
        float kn = kern[base + p];
        int lf = (tm > 0.5f) ? lab : 0;
        bool kb = (kn > 0.5f);
        float e0 = emb[(b * D_ + 0) * HW_ + p];
        float e1 = emb[(b * D_ + 1) * HW_ + p];
        float e2 = emb[(b * D_ + 2) * HW_ + p];
        float e3 = emb[(b * D_ + 3) * HW_ + p];

        #pragma unroll
        for (int l = 1; l < L_; ++l) {
            const int k = l - 1;
            bool pf = (lf == l);
            cf[k] += pf ? 1.0f : 0.0f;
            float mk = (pf && kb) ? 1.0f : 0.0f;
            ck[k] += mk;
            sm[k][0] += mk * e0;
            sm[k][1] += mk * e1;
            sm[k][2] += mk * e2;
            sm[k][3] += mk * e3;
            // p strictly increases within a thread -> first two hits are min1/min2
            bool t1 = pf && (m1[k] == HW_);
            bool t2 = pf && !t1 && (m2[k] == HW_);
            m1[k] = t1 ? p : m1[k];
            m2[k] = t2 ? p : m2[k];
        }
    }

    // wave (64-lane) shuffle reduction
    #pragma unroll
    for (int l = 0; l < NL; ++l) {
        #pragma unroll
        for (int off = 32; off > 0; off >>= 1) {
            cf[l] += __shfl_down(cf[l], off);
            ck[l] += __shfl_down(ck[l], off);
            sm[l][0] += __shfl_down(sm[l][0], off);
            sm[l][1] += __shfl_down(sm[l][1], off);
            sm[l][2] += __shfl_down(sm[l][2], off);
            sm[l][3] += __shfl_down(sm[l][3], off);
            int o1 = __shfl_down(m1[l], off);
            int o2 = __shfl_down(m2[l], off);
            // two-min combine over disjoint sets
            m2[l] = min(min(m2[l], o2), max(m1[l], o1));
            m1[l] = min(m1[l], o1);
        }
    }

    if ((tid & 63) == 0) {   // lane 0 of each of the 4 waves
        #pragma unroll
        for (int l = 0; l < NL; ++l) {
            atomicAdd(&sCntF[l + 1], cf[l]);
            atomicAdd(&sCntK[l + 1], ck[l]);
            #pragma unroll
            for (int d = 0; d < D_; ++d) atomicAdd(&sSum[(l + 1) * D_ + d], sm[l][d]);
            int old = atomicMin(&sM1[l + 1], m1[l]);
            atomicMin(&sM2[l + 1], max(old, m1[l]));
            atomicMin(&sM2[l + 1], m2[l]);
        }
    }
    __syncthreads();

    if (tid >= 1 && tid < L_) {
        gatom_add(&cntf[b * L_ + tid], sCntF[tid]);
        gatom_add(&cntk[b * L_ + tid], sCntK[tid]);
        int old = atomicMin(&firstIdx[b * L_ + tid], sM1[tid]);
        atomicMin(&secondIdx[b * L_ + tid], max(old, sM1[tid]));
        atomicMin(&secondIdx[b * L_ + tid], sM2[tid]);
    }
    if (tid >= D_ && tid < L_ * D_)
        gatom_add(&sumemb[b * L_ * D_ + tid], sSum[tid]);
}

// ---------------------------------------------------------------------------
// K3: l_agg inner pass — branchless (lf==0 contributes exactly 0), register
// accumulators + one shuffle reduction.
// ---------------------------------------------------------------------------
__global__ __launch_bounds__(BLOCK) void k_pass3(
        const float* __restrict__ emb, const int* __restrict__ inst,
        const float* __restrict__ tmask,
        const int* __restrict__ firstIdx, const int* __restrict__ secondIdx,
        const float* __restrict__ cntk, const float* __restrict__ sumemb,
        float* __restrict__ sumval) {
    __shared__ float sMean[L_ * D_];
    __shared__ float sCd[L_];
    __shared__ float sVal[L_];

    const int tid = threadIdx.x;
    const int b   = blockIdx.y;

    if (tid < L_ * D_) {
        int l = tid / D_;
        float c = fmaxf(cntk[b * L_ + l], 1.0f);
        sMean[tid] = (l > 0) ? sumemb[b * L_ * D_ + tid] / c : 0.0f;
    }
    if (tid < L_) {
        float cd = 0.0f;
        if (tid > 0) {
            const float diag = sqrtf((float)(H_ * H_ + W_ * W_));
            int f = min(firstIdx[b * L_ + tid],  HW_ - 1);
            int s = min(secondIdx[b * L_ + tid], HW_ - 1);
            float r0 = (float)(f / W_), c0 = (float)(f % W_);
            float r1 = (float)(s / W_), c1 = (float)(s % W_);
            cd = expf(sqrtf((r0 - c0) * (r0 - c0) + (r1 - c1) * (r1 - c1))
                      / diag * 0.5f);
        }
        sCd[tid]  = cd;
        sVal[tid] = 0.0f;
    }
    __syncthreads();

    const int base = b * HW_;
    float vs[NL];
    #pragma unroll
    for (int l = 0; l < NL; ++l) vs[l] = 0.f;

    #pragma unroll
    for (int it = 0; it < ITER; ++it) {
        int p = blockIdx.x * (BLOCK * ITER) + it * BLOCK + tid;
        int lab  = inst[base + p];
        float tm = tmask[base + p];
        int lf = (tm > 0.5f) ? lab : 0;
        float d2 = 0.0f;
        #pragma unroll
        for (int d = 0; d < D_; ++d) {
            float e = emb[(b * D_ + d) * HW_ + p] - sMean[lf * D_ + d];
            d2 += e * e;
        }
        float dist = sqrtf(d2);                 // d2>=0
        float x = fmaxf(sCd[lf] * dist - 0.5f, 0.0f);   // lf==0: cd=0 -> x=0
        float val = logf(x * x + 1.0f);          // x==0 -> 0
        #pragma unroll
        for (int l = 1; l < L_; ++l)
            vs[l - 1] += (lf == l) ? val : 0.0f;
    }

    #pragma unroll
    for (int l = 0; l < NL; ++l) {
        #pragma unroll
        for (int off = 32; off > 0; off >>= 1)
            vs[l] += __shfl_down(vs[l], off);
    }
    if ((tid & 63) == 0) {
        #pragma unroll
        for (int l = 0; l < NL; ++l) atomicAdd(&sVal[l + 1], vs[l]);
    }
    __syncthreads();

    if (tid >= 1 && tid < L_)
        gatom_add(&sumval[b * L_ + tid], sVal[tid]);
}

// ---------------------------------------------------------------------------
// K4: parallel epilogue — one thread per (b, i, j) term, 512 threads, 1 block.
// ---------------------------------------------------------------------------
__global__ __launch_bounds__(512) void k_final(
        const int* __restrict__ firstIdx, const int* __restrict__ secondIdx,
        const float* __restrict__ cntk, const float* __restrict__ cntf,
        const float* __restrict__ sumemb, const float* __restrict__ sumval,
        float* __restrict__ out) {
    __shared__ float sWave[8];
    const int tid = threadIdx.x;
    const int b = tid >> 6, ij = tid & 63, i = ij >> 3, j = ij & 7;
    const float diag = sqrtf((float)(H_ * H_ + W_ * W_));

    float mi[D_], mj[D_];
    {
        float ci = fmaxf(cntk[b * L_ + i], 1.0f);
        float cj = fmaxf(cntk[b * L_ + j], 1.0f);
        #pragma unroll
        for (int d = 0; d < D_; ++d) {
            mi[d] = (i > 0) ? sumemb[(b * L_ + i) * D_ + d] / ci : 0.0f;
            mj[d] = (j > 0) ? sumemb[(b * L_ + j) * D_ + d] / cj : 0.0f;
        }
    }

    float contrib = 0.0f;
    if (j == 0) {            // l_reg term for label i (i=0 gives 0)
        float d2 = 0.f;
        #pragma unroll
        for (int d = 0; d < D_; ++d) d2 += mi[d] * mi[d];
        float n = (d2 > 0.f) ? sqrtf(d2) : 0.f;
        contrib += logf(n + 1.0f) * (0.001f / (float)L_);
    }
    if (i == 0 && j >= 1) {  // l_agg term for label j
        contrib += sumval[b * L_ + j] / fmaxf(cntf[b * L_ + j], 1.0f) * (1.0f / (float)NL);
    }
    if (i >= 1 && j >= 1 && i != j) {   // l_dis pair term
        float d2 = 0.f;
        #pragma unroll
        for (int d = 0; d < D_; ++d) {
            float df = mi[d] - mj[d];
            d2 += df * df;
        }
        float Dn = (d2 > 0.f) ? sqrtf(d2) : 0.f;
        int fi = min(firstIdx[b * L_ + i],  HW_ - 1);
        int si = min(secondIdx[b * L_ + i], HW_ - 1);
        int fj = min(firstIdx[b * L_ + j],  HW_ - 1);
        int sj = min(secondIdx[b * L_ + j], HW_ - 1);
        float ssi = (float)(fi / W_) + (float)(fi % W_);
        float tti = (float)(si / W_) + (float)(si % W_);
        float ssj = (float)(fj / W_) + (float)(fj % W_);
        float ttj = (float)(sj / W_) + (float)(sj % W_);
        float dx = ssi - ssj, dy = tti - ttj;
        float dp = sqrtf(dx * dx + dy * dy);
        float coef = 1.0f - 20.0f * expf(-4.0f - 2.5f * dp / diag);
        float x = fmaxf(3.0f - coef * Dn, 0.0f);   // 2*delta_d = 3.0
        contrib += logf(x * x + 1.0f) * (1.0f / 42.0f);
    }

    #pragma unroll
    for (int off = 32; off > 0; off >>= 1)
        contrib += __shfl_down(contrib, off);
    if ((tid & 63) == 0) sWave[tid >> 6] = contrib;
    __syncthreads();
    if (tid == 0) {
        float t = 0.f;
        #pragma unroll
        for (int w = 0; w < 8; ++w) t += sWave[w];
        out[0] = t * (1.0f / (float)B_);           // LOSS_WEIGHT = 1
    }
}

extern "C" void kernel_launch(void* const* d_in, const int* in_sizes, int n_in,
                              void* d_out, int out_size, void* d_ws, size_t ws_size,
                              hipStream_t stream) {
    const float* emb   = (const float*)d_in[0];
    const int*   inst  = (const int*)  d_in[1];
    const float* kern  = (const float*)d_in[2];
    const float* tmask = (const float*)d_in[3];
    // d_in[4] = bboxes, unused by the reference

    int*   firstIdx  = (int*)d_ws;
    int*   secondIdx = firstIdx + B_ * L_;
    float* cntk      = (float*)(secondIdx + B_ * L_);
    float* cntf      = cntk + B_ * L_;
    float* sumemb    = cntf + B_ * L_;
    float* sumval    = sumemb + B_ * L_ * D_;
    float* out       = (float*)d_out;

    dim3 grid(HW_ / (BLOCK * ITER), B_);   // (200, 8)

    k_init <<<1, 256, 0, stream>>>(firstIdx, secondIdx, cntk);
    k_pass1<<<grid, BLOCK, 0, stream>>>(emb, inst, kern, tmask,
                                        firstIdx, secondIdx, cntk, cntf, sumemb);
    k_pass3<<<grid, BLOCK, 0, stream>>>(emb, inst, tmask, firstIdx, secondIdx,
                                        cntk, sumemb, sumval);
    k_final<<<1, 512, 0, stream>>>(firstIdx, secondIdx, cntk, cntf,
                                   sumemb, sumval, out);
}

// Round 3
// 159.539 us; speedup vs baseline: 1.1456x; 1.0830x over previous
//
#include <hip/hip_runtime.h>
#include <hip/hip_bf16.h>

// Problem constants (fixed by setup_inputs)
#define B_    8
#define D_    4
#define H_    640
#define W_    640
#define HW_   (H_ * W_)      // 409600
#define L_    8
#define NL    (L_ - 1)       // labels 1..7
#define BLOCK 256
#define VITER 4              // float4 iterations per thread -> 16 px/thread
#define GRIDX (HW_ / (BLOCK * 4 * VITER))   // 100

__device__ __forceinline__ void gatom_add(float* p, float v) {
    unsafeAtomicAdd(p, v);   // global_atomic_add_f32
}

// ---------------------------------------------------------------------------
// ws layout (4-byte elements):
//   int   firstIdx [64] @0     int secondIdx[64] @64
//   int   cntf_i   [64] @128   int cntk_i   [64] @192
//   float sumemb  [256] @256   float sumvalb [8] @512
// ---------------------------------------------------------------------------
__global__ void k_init(int* ib) {
    int t = threadIdx.x;
    if (t < 128) ib[t] = HW_;        // firstIdx + secondIdx
    ib[128 + t] = 0;                 // 128..383 (counts + start of sums)
    if (t < 136) ib[384 + t] = 0;    // 384..519 (rest of sums + sumvalb)
}

// ---------------------------------------------------------------------------
// K1: counts, kernel-region sums, first+second occurrence.
// Register accumulators (no spill: packed counts + launch_bounds(256,2)),
// float4 loads, one butterfly per block-slice.
// ---------------------------------------------------------------------------
__global__ __launch_bounds__(BLOCK, 2) void k_pass1(
        const float* __restrict__ emb, const int* __restrict__ inst,
        const float* __restrict__ kern, const float* __restrict__ tmask,
        int* __restrict__ firstIdx, int* __restrict__ secondIdx,
        int* __restrict__ cntf_i, int* __restrict__ cntk_i,
        float* __restrict__ sumemb) {
    __shared__ int   sCnt[L_];       // cf<<16 | ck
    __shared__ float sSum[L_ * D_];
    __shared__ int   sM1[L_], sM2[L_];

    const int tid = threadIdx.x;
    if (tid < L_) { sCnt[tid] = 0; sM1[tid] = HW_; sM2[tid] = HW_; }
    if (tid < L_ * D_) sSum[tid] = 0.f;
    __syncthreads();

    const int b = blockIdx.y;
    const int blockbase = blockIdx.x * (BLOCK * 4 * VITER);
    const float* embb = emb + (size_t)b * D_ * HW_;
    const int base = b * HW_;

    int   cnt[NL];        // cf<<16 | ck  (max 16 each, fits)
    float sm[NL][D_];
    int   m1[NL], m2[NL];
    #pragma unroll
    for (int l = 0; l < NL; ++l) {
        cnt[l] = 0; m1[l] = HW_; m2[l] = HW_;
        #pragma unroll
        for (int d = 0; d < D_; ++d) sm[l][d] = 0.f;
    }

    #pragma unroll
    for (int it = 0; it < VITER; ++it) {
        const int off = blockbase + it * (BLOCK * 4) + tid * 4;
        const int4   lab4 = *(const int4*)  (inst  + base + off);
        const float4 tm4  = *(const float4*)(tmask + base + off);
        const float4 kn4  = *(const float4*)(kern  + base + off);
        const float4 ev0  = *(const float4*)(embb + 0 * HW_ + off);
        const float4 ev1  = *(const float4*)(embb + 1 * HW_ + off);
        const float4 ev2  = *(const float4*)(embb + 2 * HW_ + off);
        const float4 ev3  = *(const float4*)(embb + 3 * HW_ + off);
        const int   labA[4] = {lab4.x, lab4.y, lab4.z, lab4.w};
        const float tmA[4]  = {tm4.x, tm4.y, tm4.z, tm4.w};
        const float knA[4]  = {kn4.x, kn4.y, kn4.z, kn4.w};
        const float e0A[4]  = {ev0.x, ev0.y, ev0.z, ev0.w};
        const float e1A[4]  = {ev1.x, ev1.y, ev1.z, ev1.w};
        const float e2A[4]  = {ev2.x, ev2.y, ev2.z, ev2.w};
        const float e3A[4]  = {ev3.x, ev3.y, ev3.z, ev3.w};

        #pragma unroll
        for (int c = 0; c < 4; ++c) {          // pixels strictly increasing
            const int p  = off + c;
            const int lf = (tmA[c] > 0.5f) ? labA[c] : 0;
            const bool kb = (knA[c] > 0.5f);
            #pragma unroll
            for (int l = 1; l < L_; ++l) {
                const int k = l - 1;
                const bool pf = (lf == l);
                const bool pk = pf && kb;
                cnt[k] += (pf ? 0x10000 : 0) + (pk ? 1 : 0);
                const float mk = pk ? 1.0f : 0.0f;
                sm[k][0] += mk * e0A[c];
                sm[k][1] += mk * e1A[c];
                sm[k][2] += mk * e2A[c];
                sm[k][3] += mk * e3A[c];
                const bool t1 = pf && (m1[k] == HW_);
                const bool t2 = pf && !t1 && (m2[k] == HW_);
                m1[k] = t1 ? p : m1[k];
                m2[k] = t2 ? p : m2[k];
            }
        }
    }

    // 64-lane butterfly (valid at lane 0)
    #pragma unroll
    for (int l = 0; l < NL; ++l) {
        #pragma unroll
        for (int off = 32; off > 0; off >>= 1) {
            cnt[l]   += __shfl_down(cnt[l], off);
            sm[l][0] += __shfl_down(sm[l][0], off);
            sm[l][1] += __shfl_down(sm[l][1], off);
            sm[l][2] += __shfl_down(sm[l][2], off);
            sm[l][3] += __shfl_down(sm[l][3], off);
            int o1 = __shfl_down(m1[l], off);
            int o2 = __shfl_down(m2[l], off);
            m2[l] = min(min(m2[l], o2), max(m1[l], o1));   // two-min combine
            m1[l] = min(m1[l], o1);
        }
    }

    if ((tid & 63) == 0) {   // lane 0 of each of 4 waves
        #pragma unroll
        for (int l = 0; l < NL; ++l) {
            atomicAdd(&sCnt[l + 1], cnt[l]);
            #pragma unroll
            for (int d = 0; d < D_; ++d) atomicAdd(&sSum[(l + 1) * D_ + d], sm[l][d]);
            int old = atomicMin(&sM1[l + 1], m1[l]);
            atomicMin(&sM2[l + 1], max(old, m1[l]));
            atomicMin(&sM2[l + 1], m2[l]);
        }
    }
    __syncthreads();

    if (tid >= 1 && tid < L_) {
        atomicAdd(&cntf_i[b * L_ + tid], sCnt[tid] >> 16);
        atomicAdd(&cntk_i[b * L_ + tid], sCnt[tid] & 0xFFFF);
        int old = atomicMin(&firstIdx[b * L_ + tid], sM1[tid]);
        atomicMin(&secondIdx[b * L_ + tid], max(old, sM1[tid]));
        atomicMin(&secondIdx[b * L_ + tid], sM2[tid]);
    }
    if (tid >= D_ && tid < L_ * D_)
        gatom_add(&sumemb[b * L_ * D_ + tid], sSum[tid]);
}

// ---------------------------------------------------------------------------
// K3: l_agg — single scalar accumulator per thread (val * 1/cntf[lf]),
// LDS lookup tables, float4 loads, one butterfly.
// ---------------------------------------------------------------------------
__global__ __launch_bounds__(BLOCK, 2) void k_pass3(
        const float* __restrict__ emb, const int* __restrict__ inst,
        const float* __restrict__ tmask,
        const int* __restrict__ firstIdx, const int* __restrict__ secondIdx,
        const int* __restrict__ cntk_i, const int* __restrict__ cntf_i,
        const float* __restrict__ sumemb, float* __restrict__ sumvalb) {
    __shared__ float4 sMean[L_];
    __shared__ float  sCd[L_], sInv[L_];
    __shared__ float  sAcc;

    const int tid = threadIdx.x;
    const int b   = blockIdx.y;

    if (tid < L_) {
        float4 mu = {0.f, 0.f, 0.f, 0.f};
        float cd = 0.f, inv = 0.f;
        if (tid > 0) {
            const float invk = 1.0f / fmaxf((float)cntk_i[b * L_ + tid], 1.0f);
            mu.x = sumemb[b * L_ * D_ + tid * D_ + 0] * invk;
            mu.y = sumemb[b * L_ * D_ + tid * D_ + 1] * invk;
            mu.z = sumemb[b * L_ * D_ + tid * D_ + 2] * invk;
            mu.w = sumemb[b * L_ * D_ + tid * D_ + 3] * invk;
            const float diag = sqrtf((float)(H_ * H_ + W_ * W_));
            int f = min(firstIdx[b * L_ + tid],  HW_ - 1);
            int s = min(secondIdx[b * L_ + tid], HW_ - 1);
            float r0 = (float)(f / W_), c0 = (float)(f % W_);
            float r1 = (float)(s / W_), c1 = (float)(s % W_);
            cd = __expf(sqrtf((r0 - c0) * (r0 - c0) + (r1 - c1) * (r1 - c1))
                        / diag * 0.5f);
            inv = 1.0f / fmaxf((float)cntf_i[b * L_ + tid], 1.0f);
        }
        sMean[tid] = mu; sCd[tid] = cd; sInv[tid] = inv;
        if (tid == 0) sAcc = 0.f;
    }
    __syncthreads();

    const int blockbase = blockIdx.x * (BLOCK * 4 * VITER);
    const float* embb = emb + (size_t)b * D_ * HW_;
    const int base = b * HW_;
    float acc = 0.f;

    #pragma unroll
    for (int it = 0; it < VITER; ++it) {
        const int off = blockbase + it * (BLOCK * 4) + tid * 4;
        const int4   lab4 = *(const int4*)  (inst  + base + off);
        const float4 tm4  = *(const float4*)(tmask + base + off);
        const float4 ev0  = *(const float4*)(embb + 0 * HW_ + off);
        const float4 ev1  = *(const float4*)(embb + 1 * HW_ + off);
        const float4 ev2  = *(const float4*)(embb + 2 * HW_ + off);
        const float4 ev3  = *(const float4*)(embb + 3 * HW_ + off);
        const int   labA[4] = {lab4.x, lab4.y, lab4.z, lab4.w};
        const float tmA[4]  = {tm4.x, tm4.y, tm4.z, tm4.w};
        const float e0A[4]  = {ev0.x, ev0.y, ev0.z, ev0.w};
        const float e1A[4]  = {ev1.x, ev1.y, ev1.z, ev1.w};
        const float e2A[4]  = {ev2.x, ev2.y, ev2.z, ev2.w};
        const float e3A[4]  = {ev3.x, ev3.y, ev3.z, ev3.w};

        #pragma unroll
        for (int c = 0; c < 4; ++c) {
            const int lf = (tmA[c] > 0.5f) ? labA[c] : 0;
            const float4 mu = sMean[lf];
            float dx = e0A[c] - mu.x, dy = e1A[c] - mu.y;
            float dz = e2A[c] - mu.z, dw = e3A[c] - mu.w;
            float d2 = dx * dx + dy * dy + dz * dz + dw * dw;
            float x  = fmaxf(sCd[lf] * sqrtf(d2) - 0.5f, 0.0f);  // lf==0 -> 0
            acc += __logf(x * x + 1.0f) * sInv[lf];
        }
    }

    #pragma unroll
    for (int off = 32; off > 0; off >>= 1)
        acc += __shfl_down(acc, off);
    if ((tid & 63) == 0) atomicAdd(&sAcc, acc);
    __syncthreads();
    if (tid == 0) gatom_add(&sumvalb[b], sAcc);
}

// ---------------------------------------------------------------------------
// K4: parallel epilogue — one thread per (b, i, j) term.
// ---------------------------------------------------------------------------
__global__ __launch_bounds__(512) void k_final(
        const int* __restrict__ firstIdx, const int* __restrict__ secondIdx,
        const int* __restrict__ cntk_i, const float* __restrict__ sumemb,
        const float* __restrict__ sumvalb, float* __restrict__ out) {
    __shared__ float sWave[8];
    const int tid = threadIdx.x;
    const int b = tid >> 6, ij = tid & 63, i = ij >> 3, j = ij & 7;
    const float diag = sqrtf((float)(H_ * H_ + W_ * W_));

    float mi[D_], mj[D_];
    {
        float ci = 1.0f / fmaxf((float)cntk_i[b * L_ + i], 1.0f);
        float cj = 1.0f / fmaxf((float)cntk_i[b * L_ + j], 1.0f);
        #pragma unroll
        for (int d = 0; d < D_; ++d) {
            mi[d] = (i > 0) ? sumemb[(b * L_ + i) * D_ + d] * ci : 0.0f;
            mj[d] = (j > 0) ? sumemb[(b * L_ + j) * D_ + d] * cj : 0.0f;
        }
    }

    float contrib = 0.0f;
    if (j == 0) {            // l_reg term for label i (i=0 gives 0)
        float d2 = 0.f;
        #pragma unroll
        for (int d = 0; d < D_; ++d) d2 += mi[d] * mi[d];
        float n = (d2 > 0.f) ? sqrtf(d2) : 0.f;
        contrib += __logf(n + 1.0f) * (0.001f / (float)L_);
    }
    if (i == 0 && j == 1)    // l_agg (already /cntf per label)
        contrib += sumvalb[b] * (1.0f / (float)NL);
    if (i >= 1 && j >= 1 && i != j) {   // l_dis pair term
        float d2 = 0.f;
        #pragma unroll
        for (int d = 0; d < D_; ++d) {
            float df = mi[d] - mj[d];
            d2 += df * df;
        }
        float Dn = (d2 > 0.f) ? sqrtf(d2) : 0.f;
        int fi = min(firstIdx[b * L_ + i],  HW_ - 1);
        int si = min(secondIdx[b * L_ + i], HW_ - 1);
        int fj = min(firstIdx[b * L_ + j],  HW_ - 1);
        int sj = min(secondIdx[b * L_ + j], HW_ - 1);
        float ssi = (float)(fi / W_) + (float)(fi % W_);
        float tti = (float)(si / W_) + (float)(si % W_);
        float ssj = (float)(fj / W_) + (float)(fj % W_);
        float ttj = (float)(sj / W_) + (float)(sj % W_);
        float dx = ssi - ssj, dy = tti - ttj;
        float dp = sqrtf(dx * dx + dy * dy);
        float coef = 1.0f - 20.0f * __expf(-4.0f - 2.5f * dp / diag);
        float x = fmaxf(3.0f - coef * Dn, 0.0f);   // 2*delta_d = 3.0
        contrib += __logf(x * x + 1.0f) * (1.0f / 42.0f);
    }

    #pragma unroll
    for (int off = 32; off > 0; off >>= 1)
        contrib += __shfl_down(contrib, off);
    if ((tid & 63) == 0) sWave[tid >> 6] = contrib;
    __syncthreads();
    if (tid == 0) {
        float t = 0.f;
        #pragma unroll
        for (int w = 0; w < 8; ++w) t += sWave[w];
        out[0] = t * (1.0f / (float)B_);           // LOSS_WEIGHT = 1
    }
}

extern "C" void kernel_launch(void* const* d_in, const int* in_sizes, int n_in,
                              void* d_out, int out_size, void* d_ws, size_t ws_size,
                              hipStream_t stream) {
    const float* emb   = (const float*)d_in[0];
    const int*   inst  = (const int*)  d_in[1];
    const float* kern  = (const float*)d_in[2];
    const float* tmask = (const float*)d_in[3];
    // d_in[4] = bboxes, unused by the reference

    int*   ib        = (int*)d_ws;
    int*   firstIdx  = ib;
    int*   secondIdx = ib + 64;
    int*   cntf_i    = ib + 128;
    int*   cntk_i    = ib + 192;
    float* sumemb    = (float*)(ib + 256);
    float* sumvalb   = (float*)(ib + 512);
    float* out       = (float*)d_out;

    dim3 grid(GRIDX, B_);   // (100, 8)

    k_init <<<1, 256, 0, stream>>>(ib);
    k_pass1<<<grid, BLOCK, 0, stream>>>(emb, inst, kern, tmask,
                                        firstIdx, secondIdx, cntf_i, cntk_i, sumemb);
    k_pass3<<<grid, BLOCK, 0, stream>>>(emb, inst, tmask, firstIdx, secondIdx,
                                        cntk_i, cntf_i, sumemb, sumvalb);
    k_final<<<1, 512, 0, stream>>>(firstIdx, secondIdx, cntk_i,
                                   sumemb, sumvalb, out);
}